// Round 2
// baseline (164.137 us; speedup 1.0000x reference)
//
#include <hip/hip_runtime.h>
#include <hip/hip_bf16.h>
#include <stdint.h>

#define NB 8192
#define DK 256
#define GAMMA 10.0f
#define BM 128          // tile M = N = 128
#define BK 64
#define NKT (DK / BK)   // 4 K-chunks

typedef short short8 __attribute__((ext_vector_type(8)));
typedef float f32x4 __attribute__((ext_vector_type(4)));

__device__ __forceinline__ unsigned short f32_to_bf16(float f) {
  uint32_t u = __builtin_bit_cast(uint32_t, f);
  u += 0x7FFFu + ((u >> 16) & 1u);   // RNE
  return (unsigned short)(u >> 16);
}

// One wave per row: 1/max(||row||,eps); gamma folded into e side; store bf16.
__global__ __launch_bounds__(256) void norm_kernel(const float* __restrict__ e,
                                                   const float* __restrict__ v,
                                                   unsigned short* __restrict__ ebf,
                                                   unsigned short* __restrict__ vbf) {
  int wave = threadIdx.x >> 6;
  int lane = threadIdx.x & 63;
  int row = blockIdx.x * 4 + wave;
  const float* src;
  unsigned short* dst;
  float mul;
  if (row < NB) {
    src = e + (size_t)row * DK; dst = ebf + (size_t)row * DK; mul = GAMMA;
  } else {
    src = v + (size_t)(row - NB) * DK; dst = vbf + (size_t)(row - NB) * DK; mul = 1.0f;
  }
  float4 x = reinterpret_cast<const float4*>(src)[lane];
  float ss = x.x * x.x + x.y * x.y + x.z * x.z + x.w * x.w;
  #pragma unroll
  for (int off = 32; off >= 1; off >>= 1) ss += __shfl_xor(ss, off);
  float s = mul / fmaxf(sqrtf(ss), 1e-8f);
  ushort4 o;
  o.x = f32_to_bf16(x.x * s);
  o.y = f32_to_bf16(x.y * s);
  o.z = f32_to_bf16(x.z * s);
  o.w = f32_to_bf16(x.w * s);
  reinterpret_cast<ushort4*>(dst)[lane] = o;
}

// m97-replica: 128x128 tile, 4 waves (2x2), BK=64 double-buffered (64 KiB LDS
// -> 2 blocks/CU), global_load_lds width=16, (r&7)<<4 XOR swizzle applied on
// BOTH the pre-swizzled global source and the ds_read address (rule 21).
__global__ __launch_bounds__(256, 2) void score_kernel(const unsigned short* __restrict__ ebf,
                                                       const unsigned short* __restrict__ vbf,
                                                       float* __restrict__ out) {
  __shared__ unsigned short lds[2][2][BM * BK];   // [buf][A/B] 16 KiB each = 64 KiB

  const int tid = threadIdx.x;
  const int w = tid >> 6;          // 0..3
  const int lane = tid & 63;
  const int lo16 = lane & 15;
  const int q4 = lane >> 4;        // 0..3
  const int wr = w >> 1;           // 0..1 (M half)
  const int wc = w & 1;            // 0..1 (N half)

  // XCD-aware bijective swizzle: 4096 blocks, 512 contiguous per XCD.
  int id = blockIdx.x;
  int nid = (id & 7) * 512 + (id >> 3);
  int bi = nid >> 6;               // 0..63
  int bj = nid & 63;

  const char* eB = (const char*)(ebf + (size_t)bi * BM * DK);
  const char* vB = (const char*)(vbf + (size_t)bj * BM * DK);

  auto stage = [&](int buf, int kt) {
    #pragma unroll
    for (int c = 0; c < 4; ++c) {
      int p = ((w * 4 + c) * 64 + lane) * 16;       // linear byte in 16 KiB tile
      int r = p >> 7;                               // row (128 B rows)
      int lc = (p & 127) ^ ((r & 7) << 4);          // inverse-swizzled logical col
      size_t goff = (size_t)r * (DK * 2) + (size_t)kt * (BK * 2) + (size_t)lc;
      unsigned short* dA = &lds[buf][0][(w * 4 + c) * 512];
      unsigned short* dB = &lds[buf][1][(w * 4 + c) * 512];
      __builtin_amdgcn_global_load_lds((const __attribute__((address_space(1))) uint32_t*)(eB + goff),
                                       (__attribute__((address_space(3))) uint32_t*)dA, 16, 0, 0);
      __builtin_amdgcn_global_load_lds((const __attribute__((address_space(1))) uint32_t*)(vB + goff),
                                       (__attribute__((address_space(3))) uint32_t*)dB, 16, 0, 0);
    }
  };

  f32x4 acc[4][4];
  #pragma unroll
  for (int m = 0; m < 4; ++m)
    #pragma unroll
    for (int n = 0; n < 4; ++n)
      #pragma unroll
      for (int q = 0; q < 4; ++q)
        acc[m][n][q] = 0.0f;

  stage(0, 0);
  __syncthreads();

  #pragma unroll
  for (int kt = 0; kt < NKT; ++kt) {
    int buf = kt & 1;
    if (kt + 1 < NKT) stage(buf ^ 1, kt + 1);
    const char* LA = (const char*)&lds[buf][0][0];
    const char* LB = (const char*)&lds[buf][1][0];
    #pragma unroll
    for (int ks = 0; ks < 2; ++ks) {
      short8 af[4];
      short8 bfr[4];
      #pragma unroll
      for (int m = 0; m < 4; ++m) {
        int r = wr * 64 + m * 16 + lo16;
        int q = r * 128 + ((ks * 64 + q4 * 16) ^ ((r & 7) << 4));
        af[m] = *(const short8*)(LA + q);
      }
      #pragma unroll
      for (int n = 0; n < 4; ++n) {
        int r = wc * 64 + n * 16 + lo16;
        int q = r * 128 + ((ks * 64 + q4 * 16) ^ ((r & 7) << 4));
        bfr[n] = *(const short8*)(LB + q);
      }
      #pragma unroll
      for (int m = 0; m < 4; ++m)
        #pragma unroll
        for (int n = 0; n < 4; ++n)
          acc[m][n] = __builtin_amdgcn_mfma_f32_16x16x32_bf16(af[m], bfr[n], acc[m][n], 0, 0, 0);
    }
    __syncthreads();
  }

  // Epilogue: E = exp(acc); row sums -> out[0..NB), col sums -> out[NB..2NB).
  // C/D layout: col = lane&15, row = (lane>>4)*4 + reg.
  float colpart[4] = {0.f, 0.f, 0.f, 0.f};
  #pragma unroll
  for (int m = 0; m < 4; ++m) {
    float rowpart[4] = {0.f, 0.f, 0.f, 0.f};
    #pragma unroll
    for (int n = 0; n < 4; ++n) {
      #pragma unroll
      for (int g = 0; g < 4; ++g) {
        float ev = __expf(acc[m][n][g]);
        rowpart[g] += ev;
        colpart[n] += ev;
      }
    }
    #pragma unroll
    for (int g = 0; g < 4; ++g) {
      float s = rowpart[g];
      s += __shfl_xor(s, 1);
      s += __shfl_xor(s, 2);
      s += __shfl_xor(s, 4);
      s += __shfl_xor(s, 8);
      if (lo16 == (m * 4 + g)) {
        int row = bi * BM + wr * 64 + m * 16 + q4 * 4 + g;
        atomicAdd(&out[row], s);
      }
    }
  }
  #pragma unroll
  for (int n = 0; n < 4; ++n) {
    float s = colpart[n];
    s += __shfl_xor(s, 16);
    s += __shfl_xor(s, 32);
    if (q4 == n) {
      int col = bj * BM + wc * 64 + n * 16 + lo16;
      atomicAdd(&out[NB + col], s);
    }
  }
}

extern "C" void kernel_launch(void* const* d_in, const int* in_sizes, int n_in,
                              void* d_out, int out_size, void* d_ws, size_t ws_size,
                              hipStream_t stream) {
  const float* e = (const float*)d_in[0];
  const float* v = (const float*)d_in[1];
  float* out = (float*)d_out;
  unsigned short* ebf = (unsigned short*)d_ws;
  unsigned short* vbf = ebf + (size_t)NB * DK;
  hipMemsetAsync(d_out, 0, (size_t)2 * NB * sizeof(float), stream);
  hipLaunchKernelGGL(norm_kernel, dim3((2 * NB) / 4), dim3(256), 0, stream, e, v, ebf, vbf);
  hipLaunchKernelGGL(score_kernel, dim3((NB / BM) * (NB / BM)), dim3(256), 0, stream, ebf, vbf, out);
}

// Round 3
// 85.822 us; speedup vs baseline: 1.9125x; 1.9125x over previous
//
#include <hip/hip_runtime.h>
#include <hip/hip_bf16.h>
#include <stdint.h>

#define NB 8192
#define DK 256
#define GAMMA 10.0f

typedef short short8 __attribute__((ext_vector_type(8)));
typedef float f32x4 __attribute__((ext_vector_type(4)));

__device__ __forceinline__ unsigned short f32_to_bf16(float f) {
  uint32_t u = __builtin_bit_cast(uint32_t, f);
  u += 0x7FFFu + ((u >> 16) & 1u);   // RNE
  return (unsigned short)(u >> 16);
}

// One wave per row: 1/max(||row||,eps); gamma folded into e side; store bf16.
__global__ __launch_bounds__(256) void norm_kernel(const float* __restrict__ e,
                                                   const float* __restrict__ v,
                                                   unsigned short* __restrict__ ebf,
                                                   unsigned short* __restrict__ vbf) {
  int wave = threadIdx.x >> 6;
  int lane = threadIdx.x & 63;
  int row = blockIdx.x * 4 + wave;
  const float* src;
  unsigned short* dst;
  float mul;
  if (row < NB) {
    src = e + (size_t)row * DK; dst = ebf + (size_t)row * DK; mul = GAMMA;
  } else {
    src = v + (size_t)(row - NB) * DK; dst = vbf + (size_t)(row - NB) * DK; mul = 1.0f;
  }
  float4 x = reinterpret_cast<const float4*>(src)[lane];
  float ss = x.x * x.x + x.y * x.y + x.z * x.z + x.w * x.w;
  #pragma unroll
  for (int off = 32; off >= 1; off >>= 1) ss += __shfl_xor(ss, off);
  float s = mul / fmaxf(sqrtf(ss), 1e-8f);
  ushort4 o;
  o.x = f32_to_bf16(x.x * s);
  o.y = f32_to_bf16(x.y * s);
  o.z = f32_to_bf16(x.z * s);
  o.w = f32_to_bf16(x.w * s);
  reinterpret_cast<ushort4*>(dst)[lane] = o;
}

// A-in-registers persistent-j structure for tiny-K GEMM:
// 256 blocks (1/CU), 8 waves (2x4). Block owns 128 e-rows x 2048 v-cols.
// A-panel (128x256) staged to LDS once -> regs A[4][8]; LDS then reused as a
// double-buffered B chunk ring [256 v-rows][64 k] (32 KiB x 2).
// XOR swizzle (r&7)<<4 on BOTH pre-swizzled global source and ds_read (rule 21).
__global__ __launch_bounds__(512, 2) void score_kernel(const unsigned short* __restrict__ ebf,
                                                       const unsigned short* __restrict__ vbf,
                                                       float* __restrict__ out) {
  __shared__ unsigned short smem[32768];   // 64 KiB

  const int tid = threadIdx.x;
  const int w = tid >> 6;          // 0..7
  const int lane = tid & 63;
  const int lo16 = lane & 15;
  const int q4 = lane >> 4;        // 0..3
  const int wr = w >> 2;           // 0..1 (M half, 64 rows)
  const int wc = w & 3;            // 0..3 (N quarter, 64 cols)

  // 256 blocks = 64 bi x 4 jc. id&7 ~ XCD: pair of XCDs shares one jc chunk
  // so concurrently-running blocks on an XCD share the same B panels in L2.
  int id = blockIdx.x;
  int xcd = id & 7;
  int s5 = id >> 3;                 // 0..31
  int jc = xcd >> 1;                // 0..3
  int bi = s5 | ((xcd & 1) << 5);   // 0..63

  const char* eP = (const char*)(ebf + (size_t)bi * 128 * DK);
  const char* vC = (const char*)(vbf + (size_t)jc * 8 * 256 * DK);  // jc chunk base

  // ---- Stage A panel (128 rows x 256 k = 64 KiB) into LDS, swizzled ----
  #pragma unroll
  for (int c = 0; c < 8; ++c) {
    int p = ((w * 8 + c) * 64 + lane) * 16;     // 0..65535 linear byte
    int r = p >> 9;                              // row (512 B rows)
    int gq = p ^ ((r & 7) << 4);                 // pre-swizzled source
    unsigned short* dst = &smem[(w * 8 + c) * 512];
    __builtin_amdgcn_global_load_lds((const __attribute__((address_space(1))) uint32_t*)(eP + gq),
                                     (__attribute__((address_space(3))) uint32_t*)dst, 16, 0, 0);
  }
  __syncthreads();

  // ---- A -> registers: A[m][ksg], row = wr*64 + m*16 + lo16, k = ksg*32 + q4*8 ----
  short8 A[4][8];
  #pragma unroll
  for (int m = 0; m < 4; ++m) {
    int row = wr * 64 + m * 16 + lo16;
    #pragma unroll
    for (int ksg = 0; ksg < 8; ++ksg) {
      int byte = row * 512 + ((ksg * 64 + q4 * 16) ^ ((row & 7) << 4));
      A[m][ksg] = *(const short8*)((const char*)smem + byte);
    }
  }
  __syncthreads();   // all waves done reading A before B overwrites LDS

  // ---- B chunk stage: [256 v-rows][64 k] = 32 KiB into buf (0/1) ----
  auto stageB = [&](int buf, int j, int kt) {
    const char* vP = vC + (size_t)j * 256 * DK * 2;
    #pragma unroll
    for (int c = 0; c < 4; ++c) {
      int p = ((w * 4 + c) * 64 + lane) * 16;   // 0..32767 linear byte in chunk
      int r = p >> 7;                            // v-row (128 B rows)
      int lc = (p & 127) ^ ((r & 7) << 4);
      size_t goff = (size_t)r * 512 + (size_t)kt * 128 + lc;
      unsigned short* dst = &smem[buf * 16384 + (w * 4 + c) * 512];
      __builtin_amdgcn_global_load_lds((const __attribute__((address_space(1))) uint32_t*)(vP + goff),
                                       (__attribute__((address_space(3))) uint32_t*)dst, 16, 0, 0);
    }
  };

  f32x4 acc[4][4];
  #pragma unroll
  for (int m = 0; m < 4; ++m)
    #pragma unroll
    for (int n = 0; n < 4; ++n)
      #pragma unroll
      for (int q = 0; q < 4; ++q)
        acc[m][n][q] = 0.0f;

  stageB(0, 0, 0);
  __syncthreads();

  for (int j = 0; j < 8; ++j) {
    #pragma unroll
    for (int kt = 0; kt < 4; ++kt) {
      int buf = kt & 1;
      if (kt < 3) stageB(buf ^ 1, j, kt + 1);
      else if (j < 7) stageB(buf ^ 1, j + 1, 0);
      const char* LB = (const char*)&smem[buf * 16384];
      #pragma unroll
      for (int ks = 0; ks < 2; ++ks) {
        short8 bfr[4];
        #pragma unroll
        for (int n = 0; n < 4; ++n) {
          int row = wc * 64 + n * 16 + lo16;
          int byte = row * 128 + ((ks * 64 + q4 * 16) ^ ((row & 7) << 4));
          bfr[n] = *(const short8*)(LB + byte);
        }
        #pragma unroll
        for (int m = 0; m < 4; ++m)
          #pragma unroll
          for (int n = 0; n < 4; ++n)
            acc[m][n] = __builtin_amdgcn_mfma_f32_16x16x32_bf16(A[m][kt * 2 + ks], bfr[n], acc[m][n], 0, 0, 0);
      }
      __syncthreads();
    }

    // ---- per-j-tile epilogue: E = exp(acc); row/col sums; reset acc ----
    // C/D layout: col = lane&15, row = (lane>>4)*4 + reg.
    int colbase = (jc * 8 + j) * 256 + wc * 64;
    float colpart[4] = {0.f, 0.f, 0.f, 0.f};
    #pragma unroll
    for (int m = 0; m < 4; ++m) {
      float rowpart[4] = {0.f, 0.f, 0.f, 0.f};
      #pragma unroll
      for (int n = 0; n < 4; ++n) {
        #pragma unroll
        for (int g = 0; g < 4; ++g) {
          float ev = __expf(acc[m][n][g]);
          rowpart[g] += ev;
          colpart[n] += ev;
          acc[m][n][g] = 0.0f;
        }
      }
      #pragma unroll
      for (int g = 0; g < 4; ++g) {
        float rs = rowpart[g];
        rs += __shfl_xor(rs, 1);
        rs += __shfl_xor(rs, 2);
        rs += __shfl_xor(rs, 4);
        rs += __shfl_xor(rs, 8);
        if (lo16 == m * 4 + g) {
          int row = bi * 128 + wr * 64 + m * 16 + q4 * 4 + g;
          atomicAdd(&out[row], rs);
        }
      }
    }
    #pragma unroll
    for (int n = 0; n < 4; ++n) {
      float cs = colpart[n];
      cs += __shfl_xor(cs, 16);
      cs += __shfl_xor(cs, 32);
      if (q4 == n) {
        atomicAdd(&out[NB + colbase + n * 16 + lo16], cs);
      }
    }
  }
}

extern "C" void kernel_launch(void* const* d_in, const int* in_sizes, int n_in,
                              void* d_out, int out_size, void* d_ws, size_t ws_size,
                              hipStream_t stream) {
  const float* e = (const float*)d_in[0];
  const float* v = (const float*)d_in[1];
  float* out = (float*)d_out;
  unsigned short* ebf = (unsigned short*)d_ws;
  unsigned short* vbf = ebf + (size_t)NB * DK;
  hipMemsetAsync(d_out, 0, (size_t)2 * NB * sizeof(float), stream);
  hipLaunchKernelGGL(norm_kernel, dim3((2 * NB) / 4), dim3(256), 0, stream, e, v, ebf, vbf);
  hipLaunchKernelGGL(score_kernel, dim3(256), dim3(512), 0, stream, ebf, vbf, out);
}